// Round 5
// baseline (12842.010 us; speedup 1.0000x reference)
//
#include <hip/hip_runtime.h>
#include <stdint.h>

// ---------------------------------------------------------------------------
// BiLSTM tagger, MI355X. Split-bf16 (hi+lo) 3-term MFMA => fp32-level accuracy.
// Per layer: pack Wih/Whh (rotating buffers) -> chunked pre-GEMM
// (pre = x@Wih.T + b) -> persistent flag-synced scan (52 wgs = 26 slices x 2
// dirs; Whh slice in LDS; h exchanged via asm sc0sc1 stores/loads through the
// L3 coherence point; flag spin likewise). x ping-pongs between two buffers
// per layer (fixes in-place overwrite when time-chunked).
// FC folded: logits = x @ (W2@W1).T + (b2 + W2@b1).
// Workspace: ~127 MB fixed + pre chunk (TC adaptive to ws_size).
// ---------------------------------------------------------------------------

typedef __attribute__((ext_vector_type(8))) short bf16x8;
typedef __attribute__((ext_vector_type(4))) float f32x4;
typedef unsigned short u16;
typedef unsigned int u32;

constexpr int kT = 512, kB = 32, kDIN = 768, kPROJ = 50;
constexpr int kHID = 409, kKH = 416, kNG = 1664, kXD = 832;
constexpr int kM = kT * kB;
constexpr int kH4 = 1636;
constexpr int kIN = 818;

#define MFMA_B16(acc, a, b) \
  acc = __builtin_amdgcn_mfma_f32_16x16x32_bf16(a, b, acc, 0, 0, 0)

__device__ __forceinline__ u16 f2bf(float x) {
  uint32_t u = __float_as_uint(x);
  uint32_t r = (u + 0x7FFFu + ((u >> 16) & 1u)) >> 16;
  return (u16)r;
}
__device__ __forceinline__ float bf2f(u16 v) {
  return __uint_as_float(((uint32_t)v) << 16);
}
__device__ __forceinline__ float sigm(float x) { return 1.f / (1.f + __expf(-x)); }
__device__ __forceinline__ float tanh_(float x) { return 1.f - 2.f / (__expf(2.f * x) + 1.f); }

// Issue-only coherent 16B load (bypass L1/L2 -> L3 coherence point).
// Must be followed by s_waitcnt vmcnt(0) + sched_barrier(0) before use.
__device__ __forceinline__ void cload(bf16x8& d, const u16* p) {
  asm volatile("global_load_dwordx4 %0, %1, off sc0 sc1" : "=v"(d) : "v"(p) : "memory");
}
__device__ __forceinline__ u32 cload_u32(const u32* p) {
  u32 v;
  asm volatile("global_load_dword %0, %1, off sc0 sc1\n\ts_waitcnt vmcnt(0)"
               : "=v"(v) : "v"(p) : "memory");
  return v;
}
__device__ __forceinline__ void cstore_u32(u32* p, u32 v) {
  asm volatile("global_store_dword %0, %1, off sc0 sc1" :: "v"(p), "v"(v) : "memory");
}

// ---------------------------------------------------------------------------
// Per-layer weight packing (pad 409->416, 818->832; pads are exactly 0).
// ---------------------------------------------------------------------------
__global__ void pack_wih_k(int layer, const float* __restrict__ Wsrc,
                           u16* __restrict__ wh, u16* __restrict__ wl) {
  const size_t total = (size_t)2 * kNG * kXD;
  for (size_t i = (size_t)blockIdx.x * blockDim.x + threadIdx.x; i < total;
       i += (size_t)gridDim.x * blockDim.x) {
    int k = (int)(i % kXD);
    size_t r1 = i / kXD;
    int row = (int)(r1 % kNG);
    int d = (int)(r1 / kNG);
    int g = row / kKH, j = row % kKH;
    float v = 0.f;
    if (j < kHID && k < kIN)
      v = Wsrc[((size_t)(layer * 2 + d) * kH4 + g * kHID + j) * kIN + k];
    u16 hb = f2bf(v);
    wh[i] = hb;
    wl[i] = f2bf(v - bf2f(hb));
  }
}

__global__ void pack_whh_k(int layer, const float* __restrict__ Wsrc,
                           u16* __restrict__ wh, u16* __restrict__ wl) {
  const size_t total = (size_t)2 * kNG * kKH;
  for (size_t i = (size_t)blockIdx.x * blockDim.x + threadIdx.x; i < total;
       i += (size_t)gridDim.x * blockDim.x) {
    int k = (int)(i % kKH);
    size_t r1 = i / kKH;
    int row = (int)(r1 % kNG);
    int d = (int)(r1 / kNG);
    int g = row / kKH, j = row % kKH;
    float v = 0.f;
    if (j < kHID && k < kHID)
      v = Wsrc[((size_t)(layer * 2 + d) * kH4 + g * kHID + j) * kHID + k];
    u16 hb = f2bf(v);
    wh[i] = hb;
    wl[i] = f2bf(v - bf2f(hb));
  }
}

__global__ void pack_bias_k(const float* __restrict__ bih,
                            const float* __restrict__ bhh,
                            float* __restrict__ bias) {
  int i = blockIdx.x * 256 + threadIdx.x;
  if (i >= 8 * kNG) return;
  int row = i % kNG, ld = i / kNG;
  int g = row / kKH, j = row % kKH;
  float v = 0.f;
  if (j < kHID) v = bih[ld * kH4 + g * kHID + j] + bhh[ld * kH4 + g * kHID + j];
  bias[i] = v;
}

__global__ void fold_fc_k(const float* __restrict__ W1, const float* __restrict__ b1,
                          const float* __restrict__ W2, const float* __restrict__ b2,
                          float* __restrict__ wfc, float* __restrict__ bfc) {
  int i = blockIdx.x * 256 + threadIdx.x;
  if (i >= 17 * kXD) return;
  int o = i / kXD, n = i % kXD;
  float s = 0.f;
  if (n < kIN) {
    for (int k = 0; k < 512; ++k) s += W2[o * 512 + k] * W1[(size_t)k * kIN + n];
  }
  wfc[i] = s;
  if (n == 0) {
    float bs = b2[o];
    for (int k = 0; k < 512; ++k) bs += W2[o * 512 + k] * b1[k];
    bfc[o] = bs;
  }
}

// ---------------------------------------------------------------------------
// Prep: ngram pool + proj; x0 = [enc(768) | proj(50) | 0(14)] as hi/lo bf16.
// Also zero-pads cols 818..831 of BOTH x buffers (ws is poisoned each call).
// ---------------------------------------------------------------------------
__global__ __launch_bounds__(256) void prep_k(const float* __restrict__ enc,
                                              const float* __restrict__ Wp,
                                              u16* __restrict__ x_h,
                                              u16* __restrict__ x_l,
                                              u16* __restrict__ y_h,
                                              u16* __restrict__ y_l) {
  const int t = blockIdx.x >> 2;
  const int b0 = (blockIdx.x & 3) * 8;
  const int tid = threadIdx.x;
  __shared__ __align__(16) float ng_s[8][kDIN];

  for (int idx = tid; idx < 8 * kDIN; idx += 256) {
    int bi = idx / kDIN, c = idx % kDIN;
    int b = b0 + bi;
    float e1 = enc[((size_t)b * kT + t) * kDIN + c];
    float ngv;
    if (t == 0)
      ngv = (e1 + enc[((size_t)b * kT + 1) * kDIN + c]) * 0.5f;
    else if (t == kT - 1)
      ngv = e1;
    else
      ngv = (enc[((size_t)b * kT + t - 1) * kDIN + c] + e1 +
             enc[((size_t)b * kT + t + 1) * kDIN + c]) * (1.f / 3.f);
    ng_s[bi][c] = ngv;
    size_t xo = ((size_t)t * kB + b) * kXD + c;
    u16 hb = f2bf(e1);
    x_h[xo] = hb;
    x_l[xo] = f2bf(e1 - bf2f(hb));
  }
  for (int idx = tid; idx < 8 * (kXD - kIN); idx += 256) {
    int bi = idx / (kXD - kIN), c = kIN + idx % (kXD - kIN);
    size_t xo = ((size_t)t * kB + b0 + bi) * kXD + c;
    x_h[xo] = 0; x_l[xo] = 0;
    y_h[xo] = 0; y_l[xo] = 0;
  }
  __syncthreads();

  const int w = tid >> 6, l_ = tid & 63;
  for (int p = w; p < kPROJ; p += 4) {
    float a0 = 0, a1 = 0, a2 = 0, a3 = 0, a4 = 0, a5 = 0, a6 = 0, a7 = 0;
    for (int j = l_; j < kDIN; j += 64) {
      float wv = Wp[(size_t)p * kDIN + j];
      a0 += wv * ng_s[0][j]; a1 += wv * ng_s[1][j];
      a2 += wv * ng_s[2][j]; a3 += wv * ng_s[3][j];
      a4 += wv * ng_s[4][j]; a5 += wv * ng_s[5][j];
      a6 += wv * ng_s[6][j]; a7 += wv * ng_s[7][j];
    }
    float acc8[8] = {a0, a1, a2, a3, a4, a5, a6, a7};
#pragma unroll
    for (int bi = 0; bi < 8; ++bi) {
      float v = acc8[bi];
      for (int off = 32; off > 0; off >>= 1) v += __shfl_down(v, off);
      if (l_ == 0) {
        size_t xo = ((size_t)t * kB + b0 + bi) * kXD + kDIN + p;
        u16 hb = f2bf(v);
        x_h[xo] = hb;
        x_l[xo] = f2bf(v - bf2f(hb));
      }
    }
  }
}

// ---------------------------------------------------------------------------
// Chunked pre-GEMM: C[mloc][n] = sum_k x[m_base+mloc][k]*W[n][k] + bias[n].
// BM=128 BN=64 BK=64, 4 waves, 3-term split-bf16, XOR-(r&7) LDS swizzle.
// ---------------------------------------------------------------------------
__global__ __launch_bounds__(256) void gemm_pre_k(
    const u16* __restrict__ Ah, const u16* __restrict__ Al,
    const u16* __restrict__ Bh, const u16* __restrict__ Bl,
    const float* __restrict__ bias, float* __restrict__ C,
    int m_base, int mtShift) {
  __shared__ __align__(16) u16 As_h[128 * 64], As_l[128 * 64];
  __shared__ __align__(16) u16 Bs_h[64 * 64], Bs_l[64 * 64];
  const int tid = threadIdx.x;
  const int l_ = tid & 63, w = tid >> 6;
  const int nt = blockIdx.x >> mtShift;
  const int mt = blockIdx.x & ((1 << mtShift) - 1);
  const int m0 = mt * 128, n0 = nt * 64;
  const int wr = (w & 1) * 64, wc = (w >> 1) * 32;

  f32x4 acc[4][2];
#pragma unroll
  for (int i = 0; i < 4; ++i)
#pragma unroll
    for (int j = 0; j < 2; ++j) acc[i][j] = f32x4{0.f, 0.f, 0.f, 0.f};

  for (int kt = 0; kt < 13; ++kt) {
    const int k0 = kt * 64;
#pragma unroll
    for (int i = 0; i < 4; ++i) {
      int ch = i * 256 + tid;
      int r = ch >> 3, kc = ch & 7;
      const size_t ga = (size_t)(m_base + m0 + r) * kXD + k0 + kc * 8;
      int dst = r * 64 + ((kc ^ (r & 7)) << 3);
      *(int4*)&As_h[dst] = *(const int4*)&Ah[ga];
      *(int4*)&As_l[dst] = *(const int4*)&Al[ga];
    }
#pragma unroll
    for (int i = 0; i < 2; ++i) {
      int ch = i * 256 + tid;
      int r = ch >> 3, kc = ch & 7;
      const size_t gb = (size_t)(n0 + r) * kXD + k0 + kc * 8;
      int dst = r * 64 + ((kc ^ (r & 7)) << 3);
      *(int4*)&Bs_h[dst] = *(const int4*)&Bh[gb];
      *(int4*)&Bs_l[dst] = *(const int4*)&Bl[gb];
    }
    __syncthreads();
#pragma unroll
    for (int ks = 0; ks < 2; ++ks) {
      bf16x8 a_h[4], a_l[4], b_h[2], b_l[2];
#pragma unroll
      for (int mi = 0; mi < 4; ++mi) {
        int r = wr + mi * 16 + (l_ & 15);
        int kc = ks * 4 + (l_ >> 4);
        int ad = r * 64 + ((kc ^ (r & 7)) << 3);
        a_h[mi] = *(const bf16x8*)&As_h[ad];
        a_l[mi] = *(const bf16x8*)&As_l[ad];
      }
#pragma unroll
      for (int ni = 0; ni < 2; ++ni) {
        int r = wc + ni * 16 + (l_ & 15);
        int kc = ks * 4 + (l_ >> 4);
        int ad = r * 64 + ((kc ^ (r & 7)) << 3);
        b_h[ni] = *(const bf16x8*)&Bs_h[ad];
        b_l[ni] = *(const bf16x8*)&Bs_l[ad];
      }
#pragma unroll
      for (int mi = 0; mi < 4; ++mi)
#pragma unroll
        for (int ni = 0; ni < 2; ++ni) {
          MFMA_B16(acc[mi][ni], a_h[mi], b_h[ni]);
          MFMA_B16(acc[mi][ni], a_h[mi], b_l[ni]);
          MFMA_B16(acc[mi][ni], a_l[mi], b_h[ni]);
        }
    }
    __syncthreads();
  }
#pragma unroll
  for (int mi = 0; mi < 4; ++mi)
#pragma unroll
    for (int ni = 0; ni < 2; ++ni) {
      int n = n0 + wc + ni * 16 + (l_ & 15);
      float bv = bias[n];
#pragma unroll
      for (int q = 0; q < 4; ++q) {
        int m = m0 + wr + mi * 16 + (l_ >> 4) * 4 + q;
        C[(size_t)m * kNG + n] = acc[mi][ni][q] + bv;
      }
    }
}

// ---------------------------------------------------------------------------
// Persistent LSTM scan chunk. grid = 52 (26 slices x 2 dirs), 256 thr/4 waves.
// Slice = 16 hid units -> 64 gate rows; Whh slice (hi+lo) in LDS (~107 KB).
// h exchange: asm sc0sc1 stores + explicit vmcnt(0) drain + barrier + flag
// store; consumers spin on flags via sc0sc1 loads. Writes layer out to xo_*.
// Slot protocol: step st reads slot st&1 (written st-1), writes slot (st+1)&1;
// slot st&1 is only rewritten at st+1, gated on ALL flags(st) => race-free.
// ---------------------------------------------------------------------------
__global__ __launch_bounds__(256) void scan_k(
    int st0, int nsteps, const float* __restrict__ pre,
    const u16* __restrict__ whhH, const u16* __restrict__ whhL,
    u16* __restrict__ xo_h, u16* __restrict__ xo_l,
    u32* __restrict__ h_hi, u32* __restrict__ h_lo,
    float* __restrict__ c_glob, u32* __restrict__ layerFlags) {
  const int tid = threadIdx.x, l_ = tid & 63, w = tid >> 6;
  const int d = blockIdx.x & 1, s = blockIdx.x >> 1;  // s in [0,26)
  const int mt = w & 1, nt2 = w >> 1;

  __shared__ __align__(16) u16 whh_s[2][64][424];
  __shared__ __align__(16) float gate_s[64][33];

  // Whh slice: local row r=g*16+j <- global gate row g*416 + s*16 + j
  for (int idx = tid; idx < 64 * kKH; idx += 256) {
    int r = idx / kKH, k = idx % kKH;
    int g = r >> 4, j = r & 15;
    size_t src = ((size_t)d * kNG + g * kKH + s * 16 + j) * kKH + k;
    whh_s[0][r][k] = whhH[src];
    whh_s[1][r][k] = whhL[src];
  }

  const int ub = tid >> 3;  // batch 0..31
  const int uu = tid & 7;   // unit pair -> units 2uu, 2uu+1
  const int hid0 = s * 16 + 2 * uu;
  float c0 = 0.f, c1 = 0.f;
  if (st0 != 0) {
    c0 = c_glob[(d * 32 + ub) * kKH + hid0];
    c1 = c_glob[(d * 32 + ub) * kKH + hid0 + 1];
  }

  const int arow = mt * 16 + (l_ & 15);
  const int kq = (l_ >> 4) * 8;
  const int lr0 = nt2 * 32 + (l_ & 15);
  const int lr1 = nt2 * 32 + 16 + (l_ & 15);
  const int bq = mt * 16 + (l_ >> 4) * 4;
  const int n0g = (lr0 >> 4) * kKH + s * 16 + (lr0 & 15);
  const int n1g = (lr1 >> 4) * kKH + s * 16 + (lr1 & 15);
  const float* pre_d = pre + (size_t)d * ((size_t)nsteps * kB) * kNG;
  u32* flg = layerFlags + (size_t)d * kT * 32;

  __syncthreads();

  float preg[2][4];
  {
    int lt = d ? (nsteps - 1) : 0;
    const float* p = pre_d + ((size_t)lt * kB + bq) * kNG;
#pragma unroll
    for (int q = 0; q < 4; ++q) {
      preg[0][q] = p[(size_t)q * kNG + n0g];
      preg[1][q] = p[(size_t)q * kNG + n1g];
    }
  }

  for (int stl = 0; stl < nsteps; ++stl) {
    const int st = st0 + stl;
    const int teff = d ? (kT - 1 - st) : st;
    f32x4 acc0, acc1;
#pragma unroll
    for (int q = 0; q < 4; ++q) { acc0[q] = preg[0][q]; acc1[q] = preg[1][q]; }

    if (st > 0) {
      // wait for all 26 producer wgs of step st-1 (this dir)
      u32* fst = flg + (size_t)(st - 1) * 32;
      if (w == 0 && l_ < 26) {
        int guard = 0;
        while (cload_u32(fst + l_) == 0u) {
          __builtin_amdgcn_s_sleep(1);
          if (++guard > (1 << 20)) break;  // pathology -> wrong output, not hang
        }
      }
      __syncthreads();
      const int slot = st & 1;
      const u16* hh = (const u16*)h_hi + (size_t)(slot * 2 + d) * kB * kKH;
      const u16* hl = (const u16*)h_lo + (size_t)(slot * 2 + d) * kB * kKH;
      bf16x8 ah[13], al[13];
#pragma unroll
      for (int ks = 0; ks < 13; ++ks) {
        cload(ah[ks], hh + arow * kKH + ks * 32 + kq);
        cload(al[ks], hl + arow * kKH + ks * 32 + kq);
      }
      asm volatile("s_waitcnt vmcnt(0)" ::: "memory");
      __builtin_amdgcn_sched_barrier(0);
#pragma unroll
      for (int ks = 0; ks < 13; ++ks) {
        bf16x8 bh0 = *(const bf16x8*)&whh_s[0][lr0][ks * 32 + kq];
        bf16x8 bl0 = *(const bf16x8*)&whh_s[1][lr0][ks * 32 + kq];
        bf16x8 bh1 = *(const bf16x8*)&whh_s[0][lr1][ks * 32 + kq];
        bf16x8 bl1 = *(const bf16x8*)&whh_s[1][lr1][ks * 32 + kq];
        MFMA_B16(acc0, ah[ks], bh0);
        MFMA_B16(acc0, ah[ks], bl0);
        MFMA_B16(acc0, al[ks], bh0);
        MFMA_B16(acc1, ah[ks], bh1);
        MFMA_B16(acc1, ah[ks], bl1);
        MFMA_B16(acc1, al[ks], bh1);
      }
    }

    if (stl + 1 < nsteps) {  // prefetch next step's pre (plain cached loads)
      int lt = d ? (nsteps - 2 - stl) : (stl + 1);
      const float* p = pre_d + ((size_t)lt * kB + bq) * kNG;
#pragma unroll
      for (int q = 0; q < 4; ++q) {
        preg[0][q] = p[(size_t)q * kNG + n0g];
        preg[1][q] = p[(size_t)q * kNG + n1g];
      }
    }

#pragma unroll
    for (int q = 0; q < 4; ++q) {
      gate_s[lr0][bq + q] = acc0[q];
      gate_s[lr1][bq + q] = acc1[q];
    }
    __syncthreads();

    {
      int j0 = 2 * uu, j1 = 2 * uu + 1;
      float gi0 = gate_s[0 + j0][ub], gf0 = gate_s[16 + j0][ub];
      float gc0 = gate_s[32 + j0][ub], go0 = gate_s[48 + j0][ub];
      float gi1 = gate_s[0 + j1][ub], gf1 = gate_s[16 + j1][ub];
      float gc1 = gate_s[32 + j1][ub], go1 = gate_s[48 + j1][ub];
      c0 = sigm(gf0) * c0 + sigm(gi0) * tanh_(gc0);
      c1 = sigm(gf1) * c1 + sigm(gi1) * tanh_(gc1);
      float h0v = sigm(go0) * tanh_(c0);
      float h1v = sigm(go1) * tanh_(c1);

      u16 hb0 = f2bf(h0v), lb0 = f2bf(h0v - bf2f(hb0));
      u16 hb1 = f2bf(h1v), lb1 = f2bf(h1v - bf2f(hb1));
      const int outslot = (st + 1) & 1;
      u32 vh = (u32)hb0 | ((u32)hb1 << 16);
      u32 vl = (u32)lb0 | ((u32)lb1 << 16);
      size_t hw = ((size_t)(outslot * 2 + d) * kB + ub) * (kKH / 2) + (hid0 >> 1);
      cstore_u32(h_hi + hw, vh);
      cstore_u32(h_lo + hw, vl);
      if (hid0 < kHID) {
        size_t xo = ((size_t)teff * kB + ub) * kXD + d * kHID + hid0;
        xo_h[xo] = hb0;
        xo_l[xo] = lb0;
        if (hid0 + 1 < kHID) {
          xo_h[xo + 1] = hb1;
          xo_l[xo + 1] = lb1;
        }
      }
    }
    // Drain own stores (h at coherence point), then barrier, then flag.
    asm volatile("s_waitcnt vmcnt(0)" ::: "memory");
    __syncthreads();
    if (tid == 0) cstore_u32(flg + (size_t)st * 32 + s, 1u);
  }

  c_glob[(d * 32 + ub) * kKH + hid0] = c0;
  c_glob[(d * 32 + ub) * kKH + hid0 + 1] = c1;
}

// ---------------------------------------------------------------------------
// FC with folded weights. Reads final x (x0 after 4 ping-pong layers).
// ---------------------------------------------------------------------------
__global__ __launch_bounds__(128) void fc_k(const u16* __restrict__ x_h,
                                            const u16* __restrict__ x_l,
                                            const float* __restrict__ wfc,
                                            const float* __restrict__ bfc,
                                            float* __restrict__ out) {
  const int m = blockIdx.x;
  const int t = m >> 5, b = m & 31;
  const int tid = threadIdx.x;
  __shared__ __align__(16) float xr[kXD];
  for (int i = tid; i < kXD; i += 128)
    xr[i] = bf2f(x_h[(size_t)m * kXD + i]) + bf2f(x_l[(size_t)m * kXD + i]);
  __syncthreads();
  const int w = tid >> 6, l_ = tid & 63;
  for (int o = w; o < 17; o += 2) {
    float acc = 0.f;
    for (int j = l_; j < kXD; j += 64) acc += xr[j] * wfc[(size_t)o * kXD + j];
    for (int off = 32; off > 0; off >>= 1) acc += __shfl_down(acc, off);
    if (l_ == 0) out[((size_t)b * kT + t) * 17 + o] = acc + bfc[o];
  }
}

// ---------------------------------------------------------------------------
extern "C" void kernel_launch(void* const* d_in, const int* in_sizes, int n_in,
                              void* d_out, int out_size, void* d_ws, size_t ws_size,
                              hipStream_t stream) {
  (void)in_sizes; (void)n_in; (void)out_size;
  const float* enc = (const float*)d_in[0];
  const float* Wp  = (const float*)d_in[1];
  const float* Wih = (const float*)d_in[2];
  const float* Whh = (const float*)d_in[3];
  const float* bih = (const float*)d_in[4];
  const float* bhh = (const float*)d_in[5];
  const float* W1  = (const float*)d_in[6];
  const float* b1  = (const float*)d_in[7];
  const float* W2  = (const float*)d_in[8];
  const float* b2  = (const float*)d_in[9];
  float* out = (float*)d_out;

  char* ws = (char*)d_ws;
  size_t off = 0;
  auto alloc = [&](size_t bytes) -> char* {
    char* p = ws + off;
    off += (bytes + 255) & ~(size_t)255;
    return p;
  };
  u16* x0_h  = (u16*)alloc((size_t)kM * kXD * 2);        // 26 MB
  u16* x0_l  = (u16*)alloc((size_t)kM * kXD * 2);
  u16* x1_h  = (u16*)alloc((size_t)kM * kXD * 2);
  u16* x1_l  = (u16*)alloc((size_t)kM * kXD * 2);
  u16* wih_h = (u16*)alloc((size_t)2 * kNG * kXD * 2);   // per-layer
  u16* wih_l = (u16*)alloc((size_t)2 * kNG * kXD * 2);
  u16* whh_h = (u16*)alloc((size_t)2 * kNG * kKH * 2);
  u16* whh_l = (u16*)alloc((size_t)2 * kNG * kKH * 2);
  float* bias = (float*)alloc((size_t)8 * kNG * 4);
  u32* h_hi  = (u32*)alloc((size_t)2 * 2 * kB * kKH * 2);  // [slot][d][b][k/2]
  u32* h_lo  = (u32*)alloc((size_t)2 * 2 * kB * kKH * 2);
  float* c_glob = (float*)alloc((size_t)2 * kB * kKH * 4);
  u32* flags = (u32*)alloc((size_t)4 * 2 * kT * 32 * 4);   // [l][d][st][32]
  float* wfc = (float*)alloc((size_t)17 * kXD * 4);
  float* bfc = (float*)alloc(32 * 4);

  // Pick largest time-chunk TC whose pre buffer fits remaining workspace.
  int TC = 0;
  {
    const int cand[7] = {512, 256, 128, 64, 32, 16, 8};
    for (int i = 0; i < 7; ++i) {
      size_t preB = (size_t)2 * cand[i] * kB * kNG * 4;
      if (off + preB <= ws_size) { TC = cand[i]; break; }
    }
  }
  if (TC == 0) return;  // workspace too small: clean (diagnosable) failure
  float* pre = (float*)alloc((size_t)2 * TC * kB * kNG * 4);
  const int mtShift = __builtin_ctz(TC / 4);
  const int nChunks = kT / TC;

  hipMemsetAsync(flags, 0, (size_t)4 * 2 * kT * 32 * 4, stream);

  pack_bias_k<<<dim3(52), dim3(256), 0, stream>>>(bih, bhh, bias);
  fold_fc_k<<<dim3(56), dim3(256), 0, stream>>>(W1, b1, W2, b2, wfc, bfc);
  prep_k<<<dim3(kT * 4), dim3(256), 0, stream>>>(enc, Wp, x0_h, x0_l, x1_h, x1_l);

  for (int l = 0; l < 4; ++l) {
    const bool even = (l & 1) == 0;
    const u16* xi_h = even ? x0_h : x1_h;
    const u16* xi_l = even ? x0_l : x1_l;
    u16* xo_h = even ? x1_h : x0_h;
    u16* xo_l = even ? x1_l : x0_l;

    pack_wih_k<<<dim3(2048), dim3(256), 0, stream>>>(l, Wih, wih_h, wih_l);
    pack_whh_k<<<dim3(1024), dim3(256), 0, stream>>>(l, Whh, whh_h, whh_l);
    for (int c = 0; c < nChunks; ++c) {
      const int st0 = c * TC;
      for (int dd = 0; dd < 2; ++dd) {
        const int m_base = (dd == 0 ? st0 : (kT - st0 - TC)) * kB;
        gemm_pre_k<<<dim3(26 << mtShift), dim3(256), 0, stream>>>(
            xi_h, xi_l, wih_h + (size_t)dd * kNG * kXD,
            wih_l + (size_t)dd * kNG * kXD, bias + (size_t)(l * 2 + dd) * kNG,
            pre + (size_t)dd * TC * kB * kNG, m_base, mtShift);
      }
      scan_k<<<dim3(52), dim3(256), 0, stream>>>(
          st0, TC, pre, whh_h, whh_l, xo_h, xo_l, h_hi, h_lo, c_glob,
          flags + (size_t)l * 2 * kT * 32);
    }
  }
  fc_k<<<dim3(kM), dim3(128), 0, stream>>>(x0_h, x0_l, wfc, bfc, out);
}

// Round 7
// 11148.741 us; speedup vs baseline: 1.1519x; 1.1519x over previous
//
#include <hip/hip_runtime.h>
#include <stdint.h>

// ---------------------------------------------------------------------------
// BiLSTM tagger, MI355X. Split-bf16 (hi+lo) 3-term MFMA => fp32-level accuracy.
// R6/R7 changes vs R5 (passed, 12842us):
//  * scan_k (1384us each, 2.7us/step, latency-bound @2% util):
//     - defer x-stores + pre-prefetch to AFTER flag store (pre-flag drain now
//       waits only 2 h-stores; stale deferred ops are oldest => vmcnt safe)
//     - counted-vmcnt ladder on the 26 coherent h-loads: vmcnt(18)/8/0 with
//       sched_barrier(0) after each, MFMA chunks overlap load returns
//     - pure-spin flag poll (no s_sleep)
//  * gemm_pre_k: global_load_lds width-16 staging with pre-swizzled global
//    source (linear LDS dest + same XOR on read; XOR is an involution).
// Everything else identical to the R5 PASS (absmax 1.95e-3).
// ---------------------------------------------------------------------------

typedef __attribute__((ext_vector_type(8))) short bf16x8;
typedef __attribute__((ext_vector_type(4))) float f32x4;
typedef unsigned short u16;
typedef unsigned int u32;

constexpr int kT = 512, kB = 32, kDIN = 768, kPROJ = 50;
constexpr int kHID = 409, kKH = 416, kNG = 1664, kXD = 832;
constexpr int kM = kT * kB;
constexpr int kH4 = 1636;
constexpr int kIN = 818;

#define MFMA_B16(acc, a, b) \
  acc = __builtin_amdgcn_mfma_f32_16x16x32_bf16(a, b, acc, 0, 0, 0)

__device__ __forceinline__ u16 f2bf(float x) {
  uint32_t u = __float_as_uint(x);
  uint32_t r = (u + 0x7FFFu + ((u >> 16) & 1u)) >> 16;
  return (u16)r;
}
__device__ __forceinline__ float bf2f(u16 v) {
  return __uint_as_float(((uint32_t)v) << 16);
}
__device__ __forceinline__ float sigm(float x) { return 1.f / (1.f + __expf(-x)); }
__device__ __forceinline__ float tanh_(float x) { return 1.f - 2.f / (__expf(2.f * x) + 1.f); }

// Issue-only coherent 16B load (bypass L1/L2 -> L3 coherence point).
// Must be followed by explicit s_waitcnt + sched_barrier(0) before use.
__device__ __forceinline__ void cload(bf16x8& d, const u16* p) {
  asm volatile("global_load_dwordx4 %0, %1, off sc0 sc1" : "=v"(d) : "v"(p) : "memory");
}
__device__ __forceinline__ u32 cload_u32(const u32* p) {
  u32 v;
  asm volatile("global_load_dword %0, %1, off sc0 sc1\n\ts_waitcnt vmcnt(0)"
               : "=v"(v) : "v"(p) : "memory");
  return v;
}
__device__ __forceinline__ void cstore_u32(u32* p, u32 v) {
  asm volatile("global_store_dword %0, %1, off sc0 sc1" :: "v"(p), "v"(v) : "memory");
}

// Async global->LDS 16B (linear LDS dest = wave-uniform base + lane*16).
__device__ __forceinline__ void gload_lds16(const u16* g, u16* l) {
  __builtin_amdgcn_global_load_lds(
      (const __attribute__((address_space(1))) unsigned int*)g,
      (__attribute__((address_space(3))) unsigned int*)l, 16, 0, 0);
}

// ---------------------------------------------------------------------------
// Per-layer weight packing (pad 409->416, 818->832; pads are exactly 0).
// ---------------------------------------------------------------------------
__global__ void pack_wih_k(int layer, const float* __restrict__ Wsrc,
                           u16* __restrict__ wh, u16* __restrict__ wl) {
  const size_t total = (size_t)2 * kNG * kXD;
  for (size_t i = (size_t)blockIdx.x * blockDim.x + threadIdx.x; i < total;
       i += (size_t)gridDim.x * blockDim.x) {
    int k = (int)(i % kXD);
    size_t r1 = i / kXD;
    int row = (int)(r1 % kNG);
    int d = (int)(r1 / kNG);
    int g = row / kKH, j = row % kKH;
    float v = 0.f;
    if (j < kHID && k < kIN)
      v = Wsrc[((size_t)(layer * 2 + d) * kH4 + g * kHID + j) * kIN + k];
    u16 hb = f2bf(v);
    wh[i] = hb;
    wl[i] = f2bf(v - bf2f(hb));
  }
}

__global__ void pack_whh_k(int layer, const float* __restrict__ Wsrc,
                           u16* __restrict__ wh, u16* __restrict__ wl) {
  const size_t total = (size_t)2 * kNG * kKH;
  for (size_t i = (size_t)blockIdx.x * blockDim.x + threadIdx.x; i < total;
       i += (size_t)gridDim.x * blockDim.x) {
    int k = (int)(i % kKH);
    size_t r1 = i / kKH;
    int row = (int)(r1 % kNG);
    int d = (int)(r1 / kNG);
    int g = row / kKH, j = row % kKH;
    float v = 0.f;
    if (j < kHID && k < kHID)
      v = Wsrc[((size_t)(layer * 2 + d) * kH4 + g * kHID + j) * kHID + k];
    u16 hb = f2bf(v);
    wh[i] = hb;
    wl[i] = f2bf(v - bf2f(hb));
  }
}

__global__ void pack_bias_k(const float* __restrict__ bih,
                            const float* __restrict__ bhh,
                            float* __restrict__ bias) {
  int i = blockIdx.x * 256 + threadIdx.x;
  if (i >= 8 * kNG) return;
  int row = i % kNG, ld = i / kNG;
  int g = row / kKH, j = row % kKH;
  float v = 0.f;
  if (j < kHID) v = bih[ld * kH4 + g * kHID + j] + bhh[ld * kH4 + g * kHID + j];
  bias[i] = v;
}

__global__ void fold_fc_k(const float* __restrict__ W1, const float* __restrict__ b1,
                          const float* __restrict__ W2, const float* __restrict__ b2,
                          float* __restrict__ wfc, float* __restrict__ bfc) {
  int i = blockIdx.x * 256 + threadIdx.x;
  if (i >= 17 * kXD) return;
  int o = i / kXD, n = i % kXD;
  float s = 0.f;
  if (n < kIN) {
    for (int k = 0; k < 512; ++k) s += W2[o * 512 + k] * W1[(size_t)k * kIN + n];
  }
  wfc[i] = s;
  if (n == 0) {
    float bs = b2[o];
    for (int k = 0; k < 512; ++k) bs += W2[o * 512 + k] * b1[k];
    bfc[o] = bs;
  }
}

// ---------------------------------------------------------------------------
// Prep: ngram pool + proj; x0 = [enc(768) | proj(50) | 0(14)] as hi/lo bf16.
// ---------------------------------------------------------------------------
__global__ __launch_bounds__(256) void prep_k(const float* __restrict__ enc,
                                              const float* __restrict__ Wp,
                                              u16* __restrict__ x_h,
                                              u16* __restrict__ x_l,
                                              u16* __restrict__ y_h,
                                              u16* __restrict__ y_l) {
  const int t = blockIdx.x >> 2;
  const int b0 = (blockIdx.x & 3) * 8;
  const int tid = threadIdx.x;
  __shared__ __align__(16) float ng_s[8][kDIN];

  for (int idx = tid; idx < 8 * kDIN; idx += 256) {
    int bi = idx / kDIN, c = idx % kDIN;
    int b = b0 + bi;
    float e1 = enc[((size_t)b * kT + t) * kDIN + c];
    float ngv;
    if (t == 0)
      ngv = (e1 + enc[((size_t)b * kT + 1) * kDIN + c]) * 0.5f;
    else if (t == kT - 1)
      ngv = e1;
    else
      ngv = (enc[((size_t)b * kT + t - 1) * kDIN + c] + e1 +
             enc[((size_t)b * kT + t + 1) * kDIN + c]) * (1.f / 3.f);
    ng_s[bi][c] = ngv;
    size_t xo = ((size_t)t * kB + b) * kXD + c;
    u16 hb = f2bf(e1);
    x_h[xo] = hb;
    x_l[xo] = f2bf(e1 - bf2f(hb));
  }
  for (int idx = tid; idx < 8 * (kXD - kIN); idx += 256) {
    int bi = idx / (kXD - kIN), c = kIN + idx % (kXD - kIN);
    size_t xo = ((size_t)t * kB + b0 + bi) * kXD + c;
    x_h[xo] = 0; x_l[xo] = 0;
    y_h[xo] = 0; y_l[xo] = 0;
  }
  __syncthreads();

  const int w = tid >> 6, l_ = tid & 63;
  for (int p = w; p < kPROJ; p += 4) {
    float a0 = 0, a1 = 0, a2 = 0, a3 = 0, a4 = 0, a5 = 0, a6 = 0, a7 = 0;
    for (int j = l_; j < kDIN; j += 64) {
      float wv = Wp[(size_t)p * kDIN + j];
      a0 += wv * ng_s[0][j]; a1 += wv * ng_s[1][j];
      a2 += wv * ng_s[2][j]; a3 += wv * ng_s[3][j];
      a4 += wv * ng_s[4][j]; a5 += wv * ng_s[5][j];
      a6 += wv * ng_s[6][j]; a7 += wv * ng_s[7][j];
    }
    float acc8[8] = {a0, a1, a2, a3, a4, a5, a6, a7};
#pragma unroll
    for (int bi = 0; bi < 8; ++bi) {
      float v = acc8[bi];
      for (int off = 32; off > 0; off >>= 1) v += __shfl_down(v, off);
      if (l_ == 0) {
        size_t xo = ((size_t)t * kB + b0 + bi) * kXD + kDIN + p;
        u16 hb = f2bf(v);
        x_h[xo] = hb;
        x_l[xo] = f2bf(v - bf2f(hb));
      }
    }
  }
}

// ---------------------------------------------------------------------------
// Chunked pre-GEMM. BM=128 BN=64 BK=64, 4 waves, 3-term split-bf16.
// Staging via global_load_lds(16B): LDS dest LINEAR in slot order, global
// source pre-swizzled (kc_src = kc ^ (r&7)); reads use the same XOR.
// ---------------------------------------------------------------------------
__global__ __launch_bounds__(256) void gemm_pre_k(
    const u16* __restrict__ Ah, const u16* __restrict__ Al,
    const u16* __restrict__ Bh, const u16* __restrict__ Bl,
    const float* __restrict__ bias, float* __restrict__ C,
    int m_base, int mtShift) {
  __shared__ __align__(16) u16 As_h[128 * 64], As_l[128 * 64];
  __shared__ __align__(16) u16 Bs_h[64 * 64], Bs_l[64 * 64];
  const int tid = threadIdx.x;
  const int l_ = tid & 63, w = tid >> 6;
  const int nt = blockIdx.x >> mtShift;
  const int mt = blockIdx.x & ((1 << mtShift) - 1);
  const int m0 = mt * 128, n0 = nt * 64;
  const int wr = (w & 1) * 64, wc = (w >> 1) * 32;

  f32x4 acc[4][2];
#pragma unroll
  for (int i = 0; i < 4; ++i)
#pragma unroll
    for (int j = 0; j < 2; ++j) acc[i][j] = f32x4{0.f, 0.f, 0.f, 0.f};

  for (int kt = 0; kt < 13; ++kt) {
    const int k0 = kt * 64;
#pragma unroll
    for (int i = 0; i < 4; ++i) {  // A: 1024 16B slots
      int slot = i * 256 + tid;
      int r = slot >> 3, kc = slot & 7;
      int kcs = kc ^ (r & 7);
      const size_t ga = (size_t)(m_base + m0 + r) * kXD + k0 + kcs * 8;
      gload_lds16(Ah + ga, &As_h[slot * 8]);
      gload_lds16(Al + ga, &As_l[slot * 8]);
    }
#pragma unroll
    for (int i = 0; i < 2; ++i) {  // B: 512 slots
      int slot = i * 256 + tid;
      int r = slot >> 3, kc = slot & 7;
      int kcs = kc ^ (r & 7);
      const size_t gb = (size_t)(n0 + r) * kXD + k0 + kcs * 8;
      gload_lds16(Bh + gb, &Bs_h[slot * 8]);
      gload_lds16(Bl + gb, &Bs_l[slot * 8]);
    }
    __syncthreads();  // drains vmcnt (gload_lds counts in vmcnt)
#pragma unroll
    for (int ks = 0; ks < 2; ++ks) {
      bf16x8 a_h[4], a_l[4], b_h[2], b_l[2];
#pragma unroll
      for (int mi = 0; mi < 4; ++mi) {
        int r = wr + mi * 16 + (l_ & 15);
        int kc = ks * 4 + (l_ >> 4);
        int ad = r * 64 + ((kc ^ (r & 7)) << 3);
        a_h[mi] = *(const bf16x8*)&As_h[ad];
        a_l[mi] = *(const bf16x8*)&As_l[ad];
      }
#pragma unroll
      for (int ni = 0; ni < 2; ++ni) {
        int r = wc + ni * 16 + (l_ & 15);
        int kc = ks * 4 + (l_ >> 4);
        int ad = r * 64 + ((kc ^ (r & 7)) << 3);
        b_h[ni] = *(const bf16x8*)&Bs_h[ad];
        b_l[ni] = *(const bf16x8*)&Bs_l[ad];
      }
#pragma unroll
      for (int mi = 0; mi < 4; ++mi)
#pragma unroll
        for (int ni = 0; ni < 2; ++ni) {
          MFMA_B16(acc[mi][ni], a_h[mi], b_h[ni]);
          MFMA_B16(acc[mi][ni], a_h[mi], b_l[ni]);
          MFMA_B16(acc[mi][ni], a_l[mi], b_h[ni]);
        }
    }
    __syncthreads();
  }
#pragma unroll
  for (int mi = 0; mi < 4; ++mi)
#pragma unroll
    for (int ni = 0; ni < 2; ++ni) {
      int n = n0 + wc + ni * 16 + (l_ & 15);
      float bv = bias[n];
#pragma unroll
      for (int q = 0; q < 4; ++q) {
        int m = m0 + wr + mi * 16 + (l_ >> 4) * 4 + q;
        C[(size_t)m * kNG + n] = acc[mi][ni][q] + bv;
      }
    }
}

// ---------------------------------------------------------------------------
// Persistent LSTM scan. grid = 52 (26 slices x 2 dirs), 256 thr / 4 waves.
// Counted-vmcnt load/MFMA ladder; x-stores + pre-prefetch deferred to after
// the flag store (shadowed by other wgs' flag waits); pure-spin poll.
// Slot protocol: step st reads h-slot st&1, writes slot (st+1)&1; a slot is
// only rewritten after ALL flags(st) posted => race-free.
// vmcnt ladder is stale-op safe: deferred ops are OLDEST, so vmcnt(18) =
// all stale + first 8 h-loads done; vmcnt(8) = first 18; vmcnt(0) = all.
// ---------------------------------------------------------------------------
__global__ __launch_bounds__(256) void scan_k(
    int st0, int nsteps, const float* __restrict__ pre,
    const u16* __restrict__ whhH, const u16* __restrict__ whhL,
    u16* __restrict__ xo_h, u16* __restrict__ xo_l,
    u32* __restrict__ h_hi, u32* __restrict__ h_lo,
    float* __restrict__ c_glob, u32* __restrict__ layerFlags) {
  const int tid = threadIdx.x, l_ = tid & 63, w = tid >> 6;
  const int d = blockIdx.x & 1, s = blockIdx.x >> 1;  // s in [0,26)
  const int mt = w & 1, nt2 = w >> 1;

  __shared__ __align__(16) u16 whh_s[2][64][424];
  __shared__ __align__(16) float gate_s[64][33];

  for (int idx = tid; idx < 64 * kKH; idx += 256) {
    int r = idx / kKH, k = idx % kKH;
    int g = r >> 4, j = r & 15;
    size_t src = ((size_t)d * kNG + g * kKH + s * 16 + j) * kKH + k;
    whh_s[0][r][k] = whhH[src];
    whh_s[1][r][k] = whhL[src];
  }

  const int ub = tid >> 3;  // batch 0..31
  const int uu = tid & 7;   // unit pair -> units 2uu, 2uu+1
  const int hid0 = s * 16 + 2 * uu;
  float c0 = 0.f, c1 = 0.f;
  if (st0 != 0) {
    c0 = c_glob[(d * 32 + ub) * kKH + hid0];
    c1 = c_glob[(d * 32 + ub) * kKH + hid0 + 1];
  }

  const int arow = mt * 16 + (l_ & 15);
  const int kq = (l_ >> 4) * 8;
  const int lr0 = nt2 * 32 + (l_ & 15);
  const int lr1 = nt2 * 32 + 16 + (l_ & 15);
  const int bq = mt * 16 + (l_ >> 4) * 4;
  const int n0g = (lr0 >> 4) * kKH + s * 16 + (lr0 & 15);
  const int n1g = (lr1 >> 4) * kKH + s * 16 + (lr1 & 15);
  const float* pre_d = pre + (size_t)d * ((size_t)nsteps * kB) * kNG;
  u32* flg = layerFlags + (size_t)d * kT * 32;

  __syncthreads();

  float preg[2][4];
  {
    int lt = d ? (nsteps - 1) : 0;
    const float* p = pre_d + ((size_t)lt * kB + bq) * kNG;
#pragma unroll
    for (int q = 0; q < 4; ++q) {
      preg[0][q] = p[(size_t)q * kNG + n0g];
      preg[1][q] = p[(size_t)q * kNG + n1g];
    }
  }

  for (int stl = 0; stl < nsteps; ++stl) {
    const int st = st0 + stl;
    const int teff = d ? (kT - 1 - st) : st;
    f32x4 acc0, acc1;
#pragma unroll
    for (int q = 0; q < 4; ++q) { acc0[q] = preg[0][q]; acc1[q] = preg[1][q]; }

    if (st > 0) {
      // wait for all 26 producer wgs of step st-1 (this dir); pure spin
      u32* fst = flg + (size_t)(st - 1) * 32;
      if (w == 0 && l_ < 26) {
        int guard = 0;
        while (cload_u32(fst + l_) == 0u) {
          if (++guard > (1 << 20)) break;  // pathology -> wrong output, not hang
        }
      }
      __syncthreads();
      const int slot = st & 1;
      const u16* hh = (const u16*)h_hi + (size_t)(slot * 2 + d) * kB * kKH;
      const u16* hl = (const u16*)h_lo + (size_t)(slot * 2 + d) * kB * kKH;
      bf16x8 ah[13], al[13];
#pragma unroll
      for (int ks = 0; ks < 13; ++ks) {  // 26 issue-only coherent loads
        cload(ah[ks], hh + arow * kKH + ks * 32 + kq);
        cload(al[ks], hl + arow * kKH + ks * 32 + kq);
      }
      asm volatile("s_waitcnt vmcnt(18)" ::: "memory");
      __builtin_amdgcn_sched_barrier(0);
#pragma unroll
      for (int ks = 0; ks < 4; ++ks) {
        bf16x8 bh0 = *(const bf16x8*)&whh_s[0][lr0][ks * 32 + kq];
        bf16x8 bl0 = *(const bf16x8*)&whh_s[1][lr0][ks * 32 + kq];
        bf16x8 bh1 = *(const bf16x8*)&whh_s[0][lr1][ks * 32 + kq];
        bf16x8 bl1 = *(const bf16x8*)&whh_s[1][lr1][ks * 32 + kq];
        MFMA_B16(acc0, ah[ks], bh0);
        MFMA_B16(acc0, ah[ks], bl0);
        MFMA_B16(acc0, al[ks], bh0);
        MFMA_B16(acc1, ah[ks], bh1);
        MFMA_B16(acc1, ah[ks], bl1);
        MFMA_B16(acc1, al[ks], bh1);
      }
      asm volatile("s_waitcnt vmcnt(8)" ::: "memory");
      __builtin_amdgcn_sched_barrier(0);
#pragma unroll
      for (int ks = 4; ks < 9; ++ks) {
        bf16x8 bh0 = *(const bf16x8*)&whh_s[0][lr0][ks * 32 + kq];
        bf16x8 bl0 = *(const bf16x8*)&whh_s[1][lr0][ks * 32 + kq];
        bf16x8 bh1 = *(const bf16x8*)&whh_s[0][lr1][ks * 32 + kq];
        bf16x8 bl1 = *(const bf16x8*)&whh_s[1][lr1][ks * 32 + kq];
        MFMA_B16(acc0, ah[ks], bh0);
        MFMA_B16(acc0, ah[ks], bl0);
        MFMA_B16(acc0, al[ks], bh0);
        MFMA_B16(acc1, ah[ks], bh1);
        MFMA_B16(acc1, ah[ks], bl1);
        MFMA_B16(acc1, al[ks], bh1);
      }
      asm volatile("s_waitcnt vmcnt(0)" ::: "memory");
      __builtin_amdgcn_sched_barrier(0);
#pragma unroll
      for (int ks = 9; ks < 13; ++ks) {
        bf16x8 bh0 = *(const bf16x8*)&whh_s[0][lr0][ks * 32 + kq];
        bf16x8 bl0 = *(const bf16x8*)&whh_s[1][lr0][ks * 32 + kq];
        bf16x8 bh1 = *(const bf16x8*)&whh_s[0][lr1][ks * 32 + kq];
        bf16x8 bl1 = *(const bf16x8*)&whh_s[1][lr1][ks * 32 + kq];
        MFMA_B16(acc0, ah[ks], bh0);
        MFMA_B16(acc0, ah[ks], bl0);
        MFMA_B16(acc0, al[ks], bh0);
        MFMA_B16(acc1, ah[ks], bh1);
        MFMA_B16(acc1, ah[ks], bl1);
        MFMA_B16(acc1, al[ks], bh1);
      }
    }

#pragma unroll
    for (int q = 0; q < 4; ++q) {
      gate_s[lr0][bq + q] = acc0[q];
      gate_s[lr1][bq + q] = acc1[q];
    }
    __syncthreads();

    u16 hb0, lb0, hb1, lb1;
    {
      int j0 = 2 * uu, j1 = 2 * uu + 1;
      float gi0 = gate_s[0 + j0][ub], gf0 = gate_s[16 + j0][ub];
      float gc0 = gate_s[32 + j0][ub], go0 = gate_s[48 + j0][ub];
      float gi1 = gate_s[0 + j1][ub], gf1 = gate_s[16 + j1][ub];
      float gc1 = gate_s[32 + j1][ub], go1 = gate_s[48 + j1][ub];
      c0 = sigm(gf0) * c0 + sigm(gi0) * tanh_(gc0);
      c1 = sigm(gf1) * c1 + sigm(gi1) * tanh_(gc1);
      float h0v = sigm(go0) * tanh_(c0);
      float h1v = sigm(go1) * tanh_(c1);

      hb0 = f2bf(h0v); lb0 = f2bf(h0v - bf2f(hb0));
      hb1 = f2bf(h1v); lb1 = f2bf(h1v - bf2f(hb1));
      const int outslot = (st + 1) & 1;
      u32 vh = (u32)hb0 | ((u32)hb1 << 16);
      u32 vl = (u32)lb0 | ((u32)lb1 << 16);
      size_t hw = ((size_t)(outslot * 2 + d) * kB + ub) * (kKH / 2) + (hid0 >> 1);
      cstore_u32(h_hi + hw, vh);
      cstore_u32(h_lo + hw, vl);
    }
    // Drain (only the 2 h-stores outstanding by now), barrier, post flag.
    asm volatile("s_waitcnt vmcnt(0)" ::: "memory");
    __syncthreads();
    if (tid == 0) cstore_u32(flg + (size_t)st * 32 + s, 1u);

    // Deferred work, shadowed by other wgs' flag waits:
    if (hid0 < kHID) {
      size_t xo = ((size_t)teff * kB + ub) * kXD + d * kHID + hid0;
      xo_h[xo] = hb0;
      xo_l[xo] = lb0;
      if (hid0 + 1 < kHID) {
        xo_h[xo + 1] = hb1;
        xo_l[xo + 1] = lb1;
      }
    }
    if (stl + 1 < nsteps) {
      int lt = d ? (nsteps - 2 - stl) : (stl + 1);
      const float* p = pre_d + ((size_t)lt * kB + bq) * kNG;
#pragma unroll
      for (int q = 0; q < 4; ++q) {
        preg[0][q] = p[(size_t)q * kNG + n0g];
        preg[1][q] = p[(size_t)q * kNG + n1g];
      }
    }
  }

  c_glob[(d * 32 + ub) * kKH + hid0] = c0;
  c_glob[(d * 32 + ub) * kKH + hid0 + 1] = c1;
}

// ---------------------------------------------------------------------------
// FC with folded weights. Reads final x (x0 after 4 ping-pong layers).
// ---------------------------------------------------------------------------
__global__ __launch_bounds__(128) void fc_k(const u16* __restrict__ x_h,
                                            const u16* __restrict__ x_l,
                                            const float* __restrict__ wfc,
                                            const float* __restrict__ bfc,
                                            float* __restrict__ out) {
  const int m = blockIdx.x;
  const int t = m >> 5, b = m & 31;
  const int tid = threadIdx.x;
  __shared__ __align__(16) float xr[kXD];
  for (int i = tid; i < kXD; i += 128)
    xr[i] = bf2f(x_h[(size_t)m * kXD + i]) + bf2f(x_l[(size_t)m * kXD + i]);
  __syncthreads();
  const int w = tid >> 6, l_ = tid & 63;
  for (int o = w; o < 17; o += 2) {
    float acc = 0.f;
    for (int j = l_; j < kXD; j += 64) acc += xr[j] * wfc[(size_t)o * kXD + j];
    for (int off = 32; off > 0; off >>= 1) acc += __shfl_down(acc, off);
    if (l_ == 0) out[((size_t)b * kT + t) * 17 + o] = acc + bfc[o];
  }
}

// ---------------------------------------------------------------------------
extern "C" void kernel_launch(void* const* d_in, const int* in_sizes, int n_in,
                              void* d_out, int out_size, void* d_ws, size_t ws_size,
                              hipStream_t stream) {
  (void)in_sizes; (void)n_in; (void)out_size;
  const float* enc = (const float*)d_in[0];
  const float* Wp  = (const float*)d_in[1];
  const float* Wih = (const float*)d_in[2];
  const float* Whh = (const float*)d_in[3];
  const float* bih = (const float*)d_in[4];
  const float* bhh = (const float*)d_in[5];
  const float* W1  = (const float*)d_in[6];
  const float* b1  = (const float*)d_in[7];
  const float* W2  = (const float*)d_in[8];
  const float* b2  = (const float*)d_in[9];
  float* out = (float*)d_out;

  char* ws = (char*)d_ws;
  size_t off = 0;
  auto alloc = [&](size_t bytes) -> char* {
    char* p = ws + off;
    off += (bytes + 255) & ~(size_t)255;
    return p;
  };
  u16* x0_h  = (u16*)alloc((size_t)kM * kXD * 2);
  u16* x0_l  = (u16*)alloc((size_t)kM * kXD * 2);
  u16* x1_h  = (u16*)alloc((size_t)kM * kXD * 2);
  u16* x1_l  = (u16*)alloc((size_t)kM * kXD * 2);
  u16* wih_h = (u16*)alloc((size_t)2 * kNG * kXD * 2);
  u16* wih_l = (u16*)alloc((size_t)2 * kNG * kXD * 2);
  u16* whh_h = (u16*)alloc((size_t)2 * kNG * kKH * 2);
  u16* whh_l = (u16*)alloc((size_t)2 * kNG * kKH * 2);
  float* bias = (float*)alloc((size_t)8 * kNG * 4);
  u32* h_hi  = (u32*)alloc((size_t)2 * 2 * kB * kKH * 2);
  u32* h_lo  = (u32*)alloc((size_t)2 * 2 * kB * kKH * 2);
  float* c_glob = (float*)alloc((size_t)2 * kB * kKH * 4);
  u32* flags = (u32*)alloc((size_t)4 * 2 * kT * 32 * 4);
  float* wfc = (float*)alloc((size_t)17 * kXD * 4);
  float* bfc = (float*)alloc(32 * 4);

  int TC = 0;
  {
    const int cand[7] = {512, 256, 128, 64, 32, 16, 8};
    for (int i = 0; i < 7; ++i) {
      size_t preB = (size_t)2 * cand[i] * kB * kNG * 4;
      if (off + preB <= ws_size) { TC = cand[i]; break; }
    }
  }
  if (TC == 0) return;
  float* pre = (float*)alloc((size_t)2 * TC * kB * kNG * 4);
  const int mtShift = __builtin_ctz(TC / 4);
  const int nChunks = kT / TC;

  hipMemsetAsync(flags, 0, (size_t)4 * 2 * kT * 32 * 4, stream);

  pack_bias_k<<<dim3(52), dim3(256), 0, stream>>>(bih, bhh, bias);
  fold_fc_k<<<dim3(56), dim3(256), 0, stream>>>(W1, b1, W2, b2, wfc, bfc);
  prep_k<<<dim3(kT * 4), dim3(256), 0, stream>>>(enc, Wp, x0_h, x0_l, x1_h, x1_l);

  for (int l = 0; l < 4; ++l) {
    const bool even = (l & 1) == 0;
    const u16* xi_h = even ? x0_h : x1_h;
    const u16* xi_l = even ? x0_l : x1_l;
    u16* xo_h = even ? x1_h : x0_h;
    u16* xo_l = even ? x1_l : x0_l;

    pack_wih_k<<<dim3(2048), dim3(256), 0, stream>>>(l, Wih, wih_h, wih_l);
    pack_whh_k<<<dim3(1024), dim3(256), 0, stream>>>(l, Whh, whh_h, whh_l);
    for (int c = 0; c < nChunks; ++c) {
      const int st0 = c * TC;
      for (int dd = 0; dd < 2; ++dd) {
        const int m_base = (dd == 0 ? st0 : (kT - st0 - TC)) * kB;
        gemm_pre_k<<<dim3(26 << mtShift), dim3(256), 0, stream>>>(
            xi_h, xi_l, wih_h + (size_t)dd * kNG * kXD,
            wih_l + (size_t)dd * kNG * kXD, bias + (size_t)(l * 2 + dd) * kNG,
            pre + (size_t)dd * TC * kB * kNG, m_base, mtShift);
      }
      scan_k<<<dim3(52), dim3(256), 0, stream>>>(
          st0, TC, pre, whh_h, whh_l, xo_h, xo_l, h_hi, h_lo, c_glob,
          flags + (size_t)l * 2 * kT * 32);
    }
  }
  fc_k<<<dim3(kM), dim3(128), 0, stream>>>(x0_h, x0_l, wfc, bfc, out);
}